// Round 14
// baseline (452.329 us; speedup 1.0000x reference)
//
#include <hip/hip_runtime.h>
#include <math.h>

// Problem constants (from reference)
#define N_NODES  50000
#define N_EDGES  800000
#define N_GRAPHS 2500
#define IN_DIM   128
#define HID      128
#define HEADS    2
#define HC       256   // HEADS*HID

typedef unsigned short u16;
typedef unsigned char  u8;
typedef unsigned int   u32;
typedef short  s8v  __attribute__((ext_vector_type(8)));   // 8 bf16 = 4 VGPRs (MFMA A/B frag)
typedef float  f4v  __attribute__((ext_vector_type(4)));   // MFMA C/D frag
typedef float  f2v  __attribute__((ext_vector_type(2)));

// bf16 helpers
__device__ inline float bf2f(u16 u) {
    union { unsigned int i; float f; } c; c.i = ((unsigned int)u) << 16; return c.f;
}
__device__ inline u16 f2bf(float x) {
    union { float f; unsigned int i; } c; c.f = x;
    unsigned int r = c.i + 0x7FFFu + ((c.i >> 16) & 1u);
    return (u16)(r >> 16);
}
__device__ inline float bflo(unsigned int u) {
    union { unsigned int i; float f; } c; c.i = u << 16; return c.f;
}
__device__ inline float bfhi(unsigned int u) {
    union { unsigned int i; float f; } c; c.i = u & 0xffff0000u; return c.f;
}
__device__ inline f2v mkf2(float a, float b) { f2v r; r.x = a; r.y = b; return r; }

// ---------------------------------------------------------------------------
// fp8 e4m3 encode/decode -- HW v_cvt path on gfx950, exact SW fallback
// ---------------------------------------------------------------------------
#if __has_builtin(__builtin_amdgcn_cvt_pk_fp8_f32) && __has_builtin(__builtin_amdgcn_cvt_pk_f32_fp8)
#define FP8_HW 1
#else
#define FP8_HW 0
#endif

__device__ inline u8 f2fp8(float x) {
#if FP8_HW
    return (u8)(__builtin_amdgcn_cvt_pk_fp8_f32(x, x, 0, false) & 0xff);
#else
    union { float f; unsigned int u; } c; c.f = x;
    unsigned int s = (c.u >> 24) & 0x80u;
    c.u &= 0x7fffffffu;
    if (c.f >= 448.f) return (u8)(s | 0x7e);
    if (c.f < 0.015625f) {                        // subnormal: m * 2^-9
        int m = (int)(c.f * 512.f + 0.5f);
        if (m >= 8) return (u8)(s | 0x08);
        return (u8)(s | m);
    }
    c.u += 0x000fffffu + ((c.u >> 20) & 1u);      // RNE at mantissa bit 20
    unsigned int e = ((c.u >> 23) & 0xffu) - 120u;
    unsigned int m = (c.u >> 20) & 7u;
    return (u8)(s | (e << 3) | m);
#endif
}

__device__ inline void fp8x8_to_f32(uint2 kd8, float* kf) {
#if FP8_HW
    f2v p0 = __builtin_amdgcn_cvt_pk_f32_fp8(kd8.x, false);
    f2v p1 = __builtin_amdgcn_cvt_pk_f32_fp8(kd8.x, true);
    f2v p2 = __builtin_amdgcn_cvt_pk_f32_fp8(kd8.y, false);
    f2v p3 = __builtin_amdgcn_cvt_pk_f32_fp8(kd8.y, true);
    kf[0] = p0.x; kf[1] = p0.y; kf[2] = p1.x; kf[3] = p1.y;
    kf[4] = p2.x; kf[5] = p2.y; kf[6] = p3.x; kf[7] = p3.y;
#else
#pragma unroll
    for (int i = 0; i < 8; ++i) {
        unsigned int b = ((i < 4) ? (kd8.x >> (8 * i)) : (kd8.y >> (8 * (i - 4)))) & 0xffu;
        unsigned int em = b & 0x7fu;
        union { unsigned int u; float f; } c;
        c.u = ((b & 0x80u) << 24) | ((em + 960u) << 20);   // normal decode (e+120)
        float fn = c.f;
        float fs = (float)(int)em * 0.001953125f;          // subnorm m*2^-9
        fs = (b & 0x80u) ? -fs : fs;
        kf[i] = (em >= 8u) ? fn : fs;
    }
#endif
}

// packed-pair decode: k2[0..3] = cols {0,1},{2,3},{4,5},{6,7}
__device__ inline void fp8x8_to_f2(uint2 kd8, f2v* k2) {
#if FP8_HW
    k2[0] = __builtin_amdgcn_cvt_pk_f32_fp8(kd8.x, false);
    k2[1] = __builtin_amdgcn_cvt_pk_f32_fp8(kd8.x, true);
    k2[2] = __builtin_amdgcn_cvt_pk_f32_fp8(kd8.y, false);
    k2[3] = __builtin_amdgcn_cvt_pk_f32_fp8(kd8.y, true);
#else
    float kf[8];
    fp8x8_to_f32(kd8, kf);
    k2[0] = mkf2(kf[0], kf[1]); k2[1] = mkf2(kf[2], kf[3]);
    k2[2] = mkf2(kf[4], kf[5]); k2[3] = mkf2(kf[6], kf[7]);
#endif
}

// ---------------------------------------------------------------------------
// init: blocks 0-48 zero deg, 49-58 zero gdeg, 59/60 int64-autodetect flags
// ---------------------------------------------------------------------------
__global__ __launch_bounds__(256) void init_kernel(
    const int* __restrict__ ei, const int* __restrict__ batch,
    int* __restrict__ deg, int* __restrict__ gdeg,
    int* __restrict__ flag_ei, int* __restrict__ flag_b)
{
    int b = blockIdx.x, t = threadIdx.x;
    if (b < 49) {
        int base = b * 1024 + t * 4;
        if (base + 3 < N_NODES) {
            *(int4*)&deg[base] = make_int4(0, 0, 0, 0);
        } else {
#pragma unroll
            for (int i = 0; i < 4; ++i) if (base + i < N_NODES) deg[base + i] = 0;
        }
    } else if (b < 59) {
        int i = (b - 49) * 256 + t;
        if (i < N_GRAPHS) gdeg[i] = 0;
    } else {
        const int* p = (b == 59) ? ei : batch;
        int ob = (b == 59) ? 1 : 40001;
        int* fl = (b == 59) ? flag_ei : flag_b;
        __shared__ int nz;
        if (t == 0) nz = 0;
        __syncthreads();
        int any = 0;
        for (int i = t; i < 1024; i += 256) if (p[ob + 2 * i] != 0) any = 1;
        if (any) atomicAdd(&nz, 1);
        __syncthreads();
        if (t == 0) *fl = (nz == 0) ? 1 : 0;
    }
}

// ---------------------------------------------------------------------------
// hist (edge dst + batch, rank capture) AND weight prep in one dispatch
// ---------------------------------------------------------------------------
#define W1_ELEMS (1024 * 128)
#define W2_ELEMS (896 * 256)
__global__ __launch_bounds__(256) void hist_prep_kernel(
    const int* __restrict__ ei, const int* __restrict__ batch,
    const int* __restrict__ flag_ei, const int* __restrict__ flag_b,
    int* __restrict__ deg, int* __restrict__ gdeg,
    int* __restrict__ rank,
    const float* __restrict__ Wq1, const float* __restrict__ Wk1,
    const float* __restrict__ Wv1, const float* __restrict__ Ws1,
    const float* __restrict__ bq1, const float* __restrict__ bk1,
    const float* __restrict__ bv1, const float* __restrict__ bs1,
    const float* __restrict__ Wq2, const float* __restrict__ Wk2,
    const float* __restrict__ Wv2, const float* __restrict__ Ws2,
    const float* __restrict__ bq2, const float* __restrict__ bk2,
    const float* __restrict__ bv2, const float* __restrict__ bs2,
    u16* __restrict__ w1T, float* __restrict__ b1cat,
    u16* __restrict__ w2T, float* __restrict__ b2cat)
{
    const int E = N_EDGES;
    int i = blockIdx.x * 256 + threadIdx.x;
    if (i < E) {
        int f = *flag_ei;
        int d = f ? ei[2 * ((size_t)E + i)] : ei[(size_t)E + i];
        if ((unsigned)d < (unsigned)N_NODES) rank[i] = atomicAdd(&deg[d], 1);
    } else if (i < E + N_NODES) {
        int j = i - E;
        int f = *flag_b;
        int g = f ? batch[2 * (size_t)j] : batch[j];
        if ((unsigned)g < (unsigned)N_GRAPHS) atomicAdd(&gdeg[g], 1);
    } else if (i < E + N_NODES + W1_ELEMS) {
        int t1 = i - E - N_NODES;
        int n = t1 >> 7, k = t1 & 127;
        int w = n >> 8, nc = n & 255;
        const float* W = (w == 0) ? Wq1 : (w == 1) ? Wk1 : (w == 2) ? Wv1 : Ws1;
        w1T[t1] = f2bf(W[k * 256 + nc]);
        if (k == 0) {
            const float* b = (w == 0) ? bq1 : (w == 1) ? bk1 : (w == 2) ? bv1 : bs1;
            b1cat[n] = b[nc];
        }
    } else if (i < E + N_NODES + W1_ELEMS + W2_ELEMS) {
        int t2 = i - E - N_NODES - W1_ELEMS;
        int n = t2 >> 8, k = t2 & 255;
        float val, bval;
        if (n < 768) {
            int w = n >> 8, nc = n & 255;
            const float* W = (w == 0) ? Wq2 : (w == 1) ? Wk2 : Wv2;
            val = W[k * 256 + nc];
            bval = ((w == 0) ? bq2 : (w == 1) ? bk2 : bv2)[nc];
        } else {
            val = Ws2[k * 128 + (n - 768)];
            bval = bs2[n - 768];
        }
        w2T[t2] = f2bf(val);
        if (k == 0) b2cat[n] = bval;
    }
}

// ---------------------------------------------------------------------------
// Parallel scan chain (proven)
// ---------------------------------------------------------------------------
__global__ void scan_local_kernel(const int* __restrict__ deg, int* __restrict__ rowptr,
                                  int* __restrict__ bsums, int n) {
    __shared__ int sh[256];
    int t = threadIdx.x;
    int base = blockIdx.x * 1024 + t * 4;
    int d0 = (base + 0 < n) ? deg[base + 0] : 0;
    int d1 = (base + 1 < n) ? deg[base + 1] : 0;
    int d2 = (base + 2 < n) ? deg[base + 2] : 0;
    int d3 = (base + 3 < n) ? deg[base + 3] : 0;
    sh[t] = d0 + d1 + d2 + d3;
    __syncthreads();
    for (int off = 1; off < 256; off <<= 1) {
        int val = 0;
        if (t >= off) val = sh[t - off];
        __syncthreads();
        if (t >= off) sh[t] += val;
        __syncthreads();
    }
    int excl = (t > 0) ? sh[t - 1] : 0;
    if (t == 255) bsums[blockIdx.x] = sh[255];
    if (base + 0 < n) rowptr[base + 0] = excl;
    if (base + 1 < n) rowptr[base + 1] = excl + d0;
    if (base + 2 < n) rowptr[base + 2] = excl + d0 + d1;
    if (base + 3 < n) rowptr[base + 3] = excl + d0 + d1 + d2;
}

// block 0: wave-scan of <=64 block sums (+ total); block 1: graph scan (2500)
__global__ __launch_bounds__(256) void scan_mid_kernel(
    int* __restrict__ bsums, int nb, int* __restrict__ rowptr_last,
    const int* __restrict__ gdeg, int* __restrict__ growptr)
{
    int t = threadIdx.x;
    if (blockIdx.x == 0) {
        if (t >= 64) return;
        int v = (t < nb) ? bsums[t] : 0;
        int incl = v;
        for (int off = 1; off < 64; off <<= 1) {
            int u = __shfl_up(incl, off);
            if (t >= off) incl += u;
        }
        if (t < nb) bsums[t] = incl - v;
        if (t == 63) *rowptr_last = incl;
    } else {
        __shared__ int sh[256];
        int base = t * 10;
        int loc[10];
        int s = 0;
#pragma unroll
        for (int i = 0; i < 10; ++i) {
            int v = (base + i < N_GRAPHS) ? gdeg[base + i] : 0;
            loc[i] = s; s += v;
        }
        sh[t] = s;
        __syncthreads();
        for (int off = 1; off < 256; off <<= 1) {
            int val = 0;
            if (t >= off) val = sh[t - off];
            __syncthreads();
            if (t >= off) sh[t] += val;
            __syncthreads();
        }
        int excl = (t > 0) ? sh[t - 1] : 0;
#pragma unroll
        for (int i = 0; i < 10; ++i)
            if (base + i < N_GRAPHS) growptr[base + i] = excl + loc[i];
        if (t == 255) growptr[N_GRAPHS] = sh[255];
    }
}

__global__ void scan_add_kernel(int* __restrict__ rowptr, const int* __restrict__ bsums,
                                int n) {
    int i = blockIdx.x * blockDim.x + threadIdx.x;
    if (i < n) rowptr[i] += bsums[i >> 10];
}

// ---------------------------------------------------------------------------
// Generic BM=64 MFMA GEMM body (gemm2 path): BK=32, XOR-swizzled LDS,
// swapped MFMA operands (packed stores), r10 register prefetch, 2 barriers.
// KV row = k-fp8[256B] | v-fp8[256B] = 512B.
// ---------------------------------------------------------------------------
template <typename AT, int KDIM, int NT>
__device__ __forceinline__ void gemm_slab_body(
    int bx, const AT* __restrict__ A, const u16* __restrict__ BT,
    const float* __restrict__ biascat,
    u16* __restrict__ C0, u8* __restrict__ KV, u16* __restrict__ C3,
    int s0, int s3, int M)
{
    __shared__ u16 As[64 * KDIM];
    __shared__ u16 Bs[128 * 32];
    int t = threadIdx.x;
    int wid = t >> 6, lane = t & 63;
    int wm = wid >> 1, wn = wid & 1;
    int row0 = bx * 64;

    if constexpr (sizeof(AT) == 4) {
#pragma unroll
        for (int i = 0; i < KDIM / 16; ++i) {
            int c = t + i * 256;
            int row = c / (KDIM / 4);
            int kq  = (c % (KDIM / 4)) * 4;
            float4 d = make_float4(0.f, 0.f, 0.f, 0.f);
            if (row0 + row < M)
                d = *(const float4*)&A[(size_t)(row0 + row) * KDIM + kq];
            ushort4 h;
            h.x = f2bf(d.x); h.y = f2bf(d.y); h.z = f2bf(d.z); h.w = f2bf(d.w);
            *(ushort4*)&As[row * KDIM + (kq ^ ((row & 7) << 3))] = h;
        }
    } else {
#pragma unroll
        for (int i = 0; i < KDIM / 32; ++i) {
            int c = t + i * 256;
            int row = c / (KDIM / 8);
            int kq  = (c % (KDIM / 8)) * 8;
            uint4 d = make_uint4(0u, 0u, 0u, 0u);
            if (row0 + row < M)
                d = *(const uint4*)&A[(size_t)(row0 + row) * KDIM + kq];
            *(uint4*)&As[row * KDIM + (kq ^ ((row & 7) << 3))] = d;
        }
    }
    __syncthreads();

    int koff = (lane >> 4) * 8;
    int mrow = wm * 32 + (lane & 15);
    int nrow = wn * 64 + (lane & 15);
    int aswz = (lane & 7) << 3;
    int bswz = (((lane & 15) >> 1) & 3) << 3;
    int nloc = (lane >> 4) * 4;

    int c0 = t, c1 = t + 256;
    int brow0 = c0 >> 2, bkq0 = (c0 & 3) * 8;
    int brow1 = c1 >> 2, bkq1 = (c1 & 3) * 8;
    int bsa0 = brow0 * 32 + (bkq0 ^ (((brow0 >> 1) & 3) << 3));
    int bsa1 = brow1 * 32 + (bkq1 ^ (((brow1 >> 1) & 3) << 3));

    const int KS  = KDIM / 32;
    const int TOT = NT * KS;

    uint4 pb0 = *(const uint4*)&BT[(size_t)brow0 * KDIM + bkq0];
    uint4 pb1 = *(const uint4*)&BT[(size_t)brow1 * KDIM + bkq1];

    for (int nt = 0; nt < NT; ++nt) {
        f4v acc[2][4];
#pragma unroll
        for (int i = 0; i < 2; ++i)
#pragma unroll
            for (int j = 0; j < 4; ++j)
#pragma unroll
                for (int r = 0; r < 4; ++r) acc[i][j][r] = 0.f;

        for (int kk = 0; kk < KS; ++kk) {
            int k0 = kk * 32;
            int s = nt * KS + kk;
            *(uint4*)&Bs[bsa0] = pb0;
            *(uint4*)&Bs[bsa1] = pb1;
            __syncthreads();
            int s1 = s + 1;
            if (s1 < TOT) {
                int n_ = s1 / KS, k_ = (s1 % KS) * 32;
                pb0 = *(const uint4*)&BT[(size_t)(n_ * 128 + brow0) * KDIM + k_ + bkq0];
                pb1 = *(const uint4*)&BT[(size_t)(n_ * 128 + brow1) * KDIM + k_ + bkq1];
            }

            s8v af[2], bf[4];
#pragma unroll
            for (int tm = 0; tm < 2; ++tm)
                af[tm] = *(const s8v*)&As[(mrow + tm * 16) * KDIM + ((k0 + koff) ^ aswz)];
#pragma unroll
            for (int tn = 0; tn < 4; ++tn)
                bf[tn] = *(const s8v*)&Bs[(nrow + tn * 16) * 32 + (koff ^ bswz)];
#pragma unroll
            for (int tm = 0; tm < 2; ++tm)
#pragma unroll
                for (int tn = 0; tn < 4; ++tn)
                    acc[tm][tn] = __builtin_amdgcn_mfma_f32_16x16x32_bf16(
                        bf[tn], af[tm], acc[tm][tn], 0, 0, 0);
            __syncthreads();
        }

        int buf = nt >> 1;
        int colb = (nt & 1) * 128;
        float4 b4s[4];
#pragma unroll
        for (int tn = 0; tn < 4; ++tn)
            b4s[tn] = *(const float4*)&biascat[nt * 128 + wn * 64 + tn * 16 + nloc];

#pragma unroll
        for (int tm = 0; tm < 2; ++tm) {
            int row = row0 + wm * 32 + tm * 16 + (lane & 15);
            if (row >= M) continue;
#pragma unroll
            for (int tn = 0; tn < 4; ++tn) {
                int ncol = colb + wn * 64 + tn * 16 + nloc;
                float v0 = acc[tm][tn][0] + b4s[tn].x;
                float v1 = acc[tm][tn][1] + b4s[tn].y;
                float v2 = acc[tm][tn][2] + b4s[tn].z;
                float v3 = acc[tm][tn][3] + b4s[tn].w;
                if (buf == 1 || buf == 2) {
                    int off = (buf == 1) ? 0 : 256;
                    u32 pk = (u32)f2fp8(v0) | ((u32)f2fp8(v1) << 8)
                           | ((u32)f2fp8(v2) << 16) | ((u32)f2fp8(v3) << 24);
                    *(u32*)&KV[(size_t)row * 512 + off + ncol] = pk;
                } else {
                    u16* Cp = (buf == 0) ? C0 : C3;
                    int stride = (buf == 0) ? s0 : s3;
                    ushort4 h;
                    h.x = f2bf(v0); h.y = f2bf(v1); h.z = f2bf(v2); h.w = f2bf(v3);
                    *(ushort4*)&Cp[(size_t)row * stride + ncol] = h;
                }
            }
        }
    }
}

// ---------------------------------------------------------------------------
// BM=128 body for gemm1 (KDIM=128, NT=8, fp32 A).  4 waves stacked on m
// (wm=wid); per wave per k-step: 2 af + 8 bf ds_reads -> 32 MFMA (4x the
// MFMA-per-barrier of BM=64 -- per-step fixed costs amortized).  LDS 40KB,
// 391 blocks, launch_bounds(256,3).
// ---------------------------------------------------------------------------
__device__ __forceinline__ void gemm1_slab128(
    int bx, const float* __restrict__ A, const u16* __restrict__ BT,
    const float* __restrict__ biascat,
    u16* __restrict__ C0, u8* __restrict__ KV, u16* __restrict__ C3,
    int s0, int s3, int M)
{
    const int KDIM = 128, NT = 8;
    __shared__ u16 As[128 * 128];
    __shared__ u16 Bs[128 * 32];
    int t = threadIdx.x;
    int wid = t >> 6, lane = t & 63;
    int row0 = bx * 128;

    // stage A: 128 rows x 128 f32 -> bf16, swizzled
#pragma unroll
    for (int i = 0; i < 16; ++i) {
        int c = t + i * 256;
        int row = c >> 5;              // 32 float4 per row
        int kq  = (c & 31) * 4;
        float4 d = make_float4(0.f, 0.f, 0.f, 0.f);
        if (row0 + row < M)
            d = *(const float4*)&A[(size_t)(row0 + row) * KDIM + kq];
        ushort4 h;
        h.x = f2bf(d.x); h.y = f2bf(d.y); h.z = f2bf(d.z); h.w = f2bf(d.w);
        *(ushort4*)&As[row * KDIM + (kq ^ ((row & 7) << 3))] = h;
    }
    __syncthreads();

    int koff = (lane >> 4) * 8;
    int mrow = wid * 32 + (lane & 15);
    int aswz = (lane & 7) << 3;
    int bswz = (((lane & 15) >> 1) & 3) << 3;
    int nloc = (lane >> 4) * 4;

    int c0 = t, c1 = t + 256;
    int brow0 = c0 >> 2, bkq0 = (c0 & 3) * 8;
    int brow1 = c1 >> 2, bkq1 = (c1 & 3) * 8;
    int bsa0 = brow0 * 32 + (bkq0 ^ (((brow0 >> 1) & 3) << 3));
    int bsa1 = brow1 * 32 + (bkq1 ^ (((brow1 >> 1) & 3) << 3));

    const int KS  = 4;            // 128/32
    const int TOT = NT * KS;      // 32

    uint4 pb0 = *(const uint4*)&BT[(size_t)brow0 * KDIM + bkq0];
    uint4 pb1 = *(const uint4*)&BT[(size_t)brow1 * KDIM + bkq1];

    for (int nt = 0; nt < NT; ++nt) {
        f4v acc[2][8];
#pragma unroll
        for (int i = 0; i < 2; ++i)
#pragma unroll
            for (int j = 0; j < 8; ++j)
#pragma unroll
                for (int r = 0; r < 4; ++r) acc[i][j][r] = 0.f;

        for (int kk = 0; kk < KS; ++kk) {
            int k0 = kk * 32;
            int s = nt * KS + kk;
            *(uint4*)&Bs[bsa0] = pb0;
            *(uint4*)&Bs[bsa1] = pb1;
            __syncthreads();
            int s1 = s + 1;
            if (s1 < TOT) {
                int n_ = s1 >> 2, k_ = (s1 & 3) * 32;
                pb0 = *(const uint4*)&BT[(size_t)(n_ * 128 + brow0) * KDIM + k_ + bkq0];
                pb1 = *(const uint4*)&BT[(size_t)(n_ * 128 + brow1) * KDIM + k_ + bkq1];
            }

            s8v af[2], bf[8];
#pragma unroll
            for (int tm = 0; tm < 2; ++tm)
                af[tm] = *(const s8v*)&As[(mrow + tm * 16) * KDIM + ((k0 + koff) ^ aswz)];
#pragma unroll
            for (int tn = 0; tn < 8; ++tn)
                bf[tn] = *(const s8v*)&Bs[(tn * 16 + (lane & 15)) * 32 + (koff ^ bswz)];
#pragma unroll
            for (int tm = 0; tm < 2; ++tm)
#pragma unroll
                for (int tn = 0; tn < 8; ++tn)
                    acc[tm][tn] = __builtin_amdgcn_mfma_f32_16x16x32_bf16(
                        bf[tn], af[tm], acc[tm][tn], 0, 0, 0);
            __syncthreads();
        }

        int buf = nt >> 1;
        int colb = (nt & 1) * 128;
#pragma unroll
        for (int tm = 0; tm < 2; ++tm) {
            int row = row0 + wid * 32 + tm * 16 + (lane & 15);
            if (row >= M) continue;
#pragma unroll
            for (int tn = 0; tn < 8; ++tn) {
                float4 b4 = *(const float4*)&biascat[nt * 128 + tn * 16 + nloc];
                int ncol = colb + tn * 16 + nloc;
                float v0 = acc[tm][tn][0] + b4.x;
                float v1 = acc[tm][tn][1] + b4.y;
                float v2 = acc[tm][tn][2] + b4.z;
                float v3 = acc[tm][tn][3] + b4.w;
                if (buf == 1 || buf == 2) {
                    int off = (buf == 1) ? 0 : 256;
                    u32 pk = (u32)f2fp8(v0) | ((u32)f2fp8(v1) << 8)
                           | ((u32)f2fp8(v2) << 16) | ((u32)f2fp8(v3) << 24);
                    *(u32*)&KV[(size_t)row * 512 + off + ncol] = pk;
                } else {
                    u16* Cp = (buf == 0) ? C0 : C3;
                    int stride = (buf == 0) ? s0 : s3;
                    ushort4 h;
                    h.x = f2bf(v0); h.y = f2bf(v1); h.z = f2bf(v2); h.w = f2bf(v3);
                    *(ushort4*)&Cp[(size_t)row * stride + ncol] = h;
                }
            }
        }
    }
}

#define GB1 391   // ceil(50000/128)
#define GB2 782   // ceil(50000/64)

// Layer-1 GEMM (BM=128) with atomic-free edge scatter as trailing blocks.
__global__ __launch_bounds__(256, 3) void gemm1_scatter_kernel(
    const float* __restrict__ A, const u16* __restrict__ BT,
    const float* __restrict__ biascat,
    u16* __restrict__ C0, u8* __restrict__ KV, u16* __restrict__ C3,
    int s0, int s3, int M,
    const int* __restrict__ ei, const float* __restrict__ ea,
    const int* __restrict__ flag, const int* __restrict__ rowptr,
    const int* __restrict__ rank, u32* __restrict__ edges)
{
    if (blockIdx.x < GB1) {
        gemm1_slab128(blockIdx.x, A, BT, biascat, C0, KV, C3, s0, s3, M);
    } else {
        const int E = N_EDGES;
        int i = (blockIdx.x - GB1) * 256 + threadIdx.x;
        if (i >= E) return;
        int f = *flag;
        int s = f ? ei[2 * (size_t)i] : ei[i];
        int d = f ? ei[2 * ((size_t)E + i)] : ei[(size_t)E + i];
        if ((unsigned)d >= (unsigned)N_NODES) return;
        if ((unsigned)s >= (unsigned)N_NODES) s = 0;
        int p = rowptr[d] + rank[i];
        u32 rec = (u32)(s & 0xffff) | ((u32)f2bf(ea[i]) << 16);
        edges[p] = rec;
    }
}

__global__ __launch_bounds__(256, 4) void gemm2_kernel(
    const u16* __restrict__ A, const u16* __restrict__ BT,
    const float* __restrict__ biascat,
    u16* __restrict__ C0, u8* __restrict__ KV, u16* __restrict__ C3,
    int s0, int s3, int M)
{
    gemm_slab_body<u16, 256, 7>(blockIdx.x, A, BT, biascat,
                                C0, KV, C3, s0, s3, M);
}

// ---------------------------------------------------------------------------
// Attention: wave per node, 8 cols/lane, 8 edges/step (4 per 32-lane half).
// No online max (reference-invariant softmax, alpha O(1), exp2 clamp 80).
// KV row (512B): k-fp8[256B] | v-fp8[256B].  Edge rec 4B: u16 src | bf16 ae.
// LAYER==2 writes h2 as bf16 (feeds only the mean-pool; halves the traffic).
// ---------------------------------------------------------------------------
template <int LAYER>
__global__ __launch_bounds__(256) void attn_node(
    const u16* __restrict__ q, const u8* __restrict__ kv,
    const float* __restrict__ We, const u16* __restrict__ skip,
    const int* __restrict__ rowptr, const u32* __restrict__ edges,
    void* __restrict__ hout, int N)
{
    int wave = (blockIdx.x * blockDim.x + threadIdx.x) >> 6;
    int lane = threadIdx.x & 63;
    if (wave >= N) return;
    int n = wave;
    int half = lane >> 5;
    int cl   = lane & 31;
    // scale * log2(e) = (1/sqrt(128)) * 1.4426950408889634
    const float scale2 = 0.12751743558136835f;

    uint4 qd = *(const uint4*)&q[(size_t)n * HC + cl * 8];
    f2v q2[4];
    q2[0] = mkf2(bflo(qd.x), bfhi(qd.x));
    q2[1] = mkf2(bflo(qd.y), bfhi(qd.y));
    q2[2] = mkf2(bflo(qd.z), bfhi(qd.z));
    q2[3] = mkf2(bflo(qd.w), bfhi(qd.w));
    float4 wlo = *(const float4*)&We[cl * 8];
    float4 whi = *(const float4*)&We[cl * 8 + 4];
    f2v w2[4];
    w2[0] = mkf2(wlo.x, wlo.y); w2[1] = mkf2(wlo.z, wlo.w);
    w2[2] = mkf2(whi.x, whi.y); w2[3] = mkf2(whi.z, whi.w);

    f2v qw2 = q2[0] * w2[0];
    qw2 += q2[1] * w2[1];
    qw2 += q2[2] * w2[2];
    qw2 += q2[3] * w2[3];
    float qw = qw2.x + qw2.y;
    qw += __shfl_xor(qw, 1);
    qw += __shfl_xor(qw, 2);
    qw += __shfl_xor(qw, 4);
    qw += __shfl_xor(qw, 8);

    int e0 = rowptr[n], e1 = rowptr[n + 1];
    float ll0 = 0.f, ll1 = 0.f;
    float pa0 = 0.f, pa1 = 0.f;
    f2v a0[4], a1[4];
#pragma unroll
    for (int i = 0; i < 4; ++i) { a0[i] = mkf2(0.f, 0.f); a1[i] = mkf2(0.f, 0.f); }

    int steps = (e1 - e0 + 7) >> 3;
    for (int st = 0; st < steps; ++st) {
        int eb = e0 + 8 * st + half;
        u32 rec[4]; bool act[4];
#pragma unroll
        for (int j = 0; j < 4; ++j) {
            int ex = eb + 2 * j;
            act[j] = ex < e1;
            rec[j] = edges[act[j] ? ex : e0];
        }
        uint2 kd[4], vd[4]; float ae[4];
#pragma unroll
        for (int j = 0; j < 4; ++j) {
            const u8* base = kv + (size_t)(rec[j] & 0xffffu) * 512;
            kd[j] = *(const uint2*)(base + cl * 8);
            vd[j] = *(const uint2*)(base + 256 + cl * 8);
            ae[j] = bfhi(rec[j]);
        }
#pragma unroll
        for (int j = 0; j < 4; ++j) {
            f2v k2[4], v2[4];
            fp8x8_to_f2(kd[j], k2);
            fp8x8_to_f2(vd[j], v2);
            f2v d2 = q2[0] * k2[0];
            d2 += q2[1] * k2[1];
            d2 += q2[2] * k2[2];
            d2 += q2[3] * k2[3];
            float d = d2.x + d2.y;
            d += __shfl_xor(d, 1);
            d += __shfl_xor(d, 2);
            d += __shfl_xor(d, 4);
            d += __shfl_xor(d, 8);
            float alpha = act[j] ? fmaf(ae[j], qw, d) * scale2 : -16384.f;
            float p = exp2f(fminf(alpha, 80.f));
            f2v p2 = mkf2(p, p);
            if (j & 1) {
                ll1 += p;
                pa1 = fmaf(p, ae[j], pa1);
                a1[0] += p2 * v2[0];
                a1[1] += p2 * v2[1];
                a1[2] += p2 * v2[2];
                a1[3] += p2 * v2[3];
            } else {
                ll0 += p;
                pa0 = fmaf(p, ae[j], pa0);
                a0[0] += p2 * v2[0];
                a0[1] += p2 * v2[1];
                a0[2] += p2 * v2[2];
                a0[3] += p2 * v2[3];
            }
        }
    }

    float l = ll0 + ll1;
    float pa = pa0 + pa1;
    float acc[8];
#pragma unroll
    for (int i = 0; i < 4; ++i) {
        f2v v = a0[i] + a1[i];
        acc[2 * i] = v.x; acc[2 * i + 1] = v.y;
    }

    l += __shfl_xor(l, 32);
    pa += __shfl_xor(pa, 32);
#pragma unroll
    for (int i = 0; i < 8; ++i) acc[i] += __shfl_xor(acc[i], 32);

    float wf[8];
    wf[0] = w2[0].x; wf[1] = w2[0].y; wf[2] = w2[1].x; wf[3] = w2[1].y;
    wf[4] = w2[2].x; wf[5] = w2[2].y; wf[6] = w2[3].x; wf[7] = w2[3].y;

    float inv = (l > 0.f) ? 1.f / l : 0.f;
    float o[8];
#pragma unroll
    for (int i = 0; i < 8; ++i) o[i] = fmaf(pa, wf[i], acc[i]) * inv;

    if constexpr (LAYER == 1) {
        if (half == 0) {
            uint4 sd = *(const uint4*)&skip[(size_t)n * HC + cl * 8];
            float sf[8];
            sf[0] = bflo(sd.x); sf[1] = bfhi(sd.x);
            sf[2] = bflo(sd.y); sf[3] = bfhi(sd.y);
            sf[4] = bflo(sd.z); sf[5] = bfhi(sd.z);
            sf[6] = bflo(sd.w); sf[7] = bfhi(sd.w);
            ushort4 o4a, o4b;
            o4a.x = f2bf(fmaxf(0.f, o[0] + sf[0]));
            o4a.y = f2bf(fmaxf(0.f, o[1] + sf[1]));
            o4a.z = f2bf(fmaxf(0.f, o[2] + sf[2]));
            o4a.w = f2bf(fmaxf(0.f, o[3] + sf[3]));
            o4b.x = f2bf(fmaxf(0.f, o[4] + sf[4]));
            o4b.y = f2bf(fmaxf(0.f, o[5] + sf[5]));
            o4b.z = f2bf(fmaxf(0.f, o[6] + sf[6]));
            o4b.w = f2bf(fmaxf(0.f, o[7] + sf[7]));
            u16* hp = (u16*)hout + (size_t)n * HC + cl * 8;
            *(ushort4*)hp = o4a;
            *(ushort4*)(hp + 4) = o4b;
        }
    } else {
#pragma unroll
        for (int i = 0; i < 8; ++i) {
            float t2 = __shfl_xor(o[i], 16);
            o[i] = 0.5f * (o[i] + t2);
        }
        if (lane < 16) {
            uint4 sd = *(const uint4*)&skip[(size_t)n * HID + lane * 8];
            float sf[8];
            sf[0] = bflo(sd.x); sf[1] = bfhi(sd.x);
            sf[2] = bflo(sd.y); sf[3] = bfhi(sd.y);
            sf[4] = bflo(sd.z); sf[5] = bfhi(sd.z);
            sf[6] = bflo(sd.w); sf[7] = bfhi(sd.w);
            ushort4 h2a, h2b;
            h2a.x = f2bf(o[0] + sf[0]); h2a.y = f2bf(o[1] + sf[1]);
            h2a.z = f2bf(o[2] + sf[2]); h2a.w = f2bf(o[3] + sf[3]);
            h2b.x = f2bf(o[4] + sf[4]); h2b.y = f2bf(o[5] + sf[5]);
            h2b.z = f2bf(o[6] + sf[6]); h2b.w = f2bf(o[7] + sf[7]);
            u16* hp = (u16*)hout + (size_t)n * HID + lane * 8;
            *(ushort4*)hp = h2a;
            *(ushort4*)(hp + 4) = h2b;
        }
    }
}

// ---------------------------------------------------------------------------
// Atomic-free pooling over bf16 h2: one wave per graph (batch is sorted)
// ---------------------------------------------------------------------------
__global__ __launch_bounds__(256) void pool_kernel(
    const u16* __restrict__ h2, const int* __restrict__ growptr,
    float* __restrict__ out) {
    int wave = (blockIdx.x * blockDim.x + threadIdx.x) >> 6;
    int lane = threadIdx.x & 63;
    if (wave >= N_GRAPHS) return;
    int r0 = growptr[wave], r1 = growptr[wave + 1];
    float sx = 0.f, sy = 0.f;
    for (int r = r0; r < r1; ++r) {
        u32 v = *(const u32*)&h2[(size_t)r * HID + lane * 2];
        sx += bflo(v); sy += bfhi(v);
    }
    float inv = 1.f / fmaxf((float)(r1 - r0), 1.f);
    float2 o; o.x = sx * inv; o.y = sy * inv;
    *(float2*)&out[(size_t)wave * HID + lane * 2] = o;
}

// ---------------------------------------------------------------------------
// Launch: 10 dispatches. ws ~100 MB. KV row = k-fp8[256B] | v-fp8[256B].
// Edge records 4B. Scatter rank-based. gemm1 BM=128. h2 bf16.
// ---------------------------------------------------------------------------
extern "C" void kernel_launch(void* const* d_in, const int* in_sizes, int n_in,
                              void* d_out, int out_size, void* d_ws, size_t ws_size,
                              hipStream_t stream) {
    const float* x    = (const float*)d_in[0];
    const int*   ei   = (const int*)d_in[1];
    const int*   batch= (const int*)d_in[2];
    const float* ea   = (const float*)d_in[3];
    const float* Wq1  = (const float*)d_in[4];
    const float* bq1  = (const float*)d_in[5];
    const float* Wk1  = (const float*)d_in[6];
    const float* bk1  = (const float*)d_in[7];
    const float* Wv1  = (const float*)d_in[8];
    const float* bv1  = (const float*)d_in[9];
    const float* We1  = (const float*)d_in[10];
    const float* Ws1  = (const float*)d_in[11];
    const float* bs1  = (const float*)d_in[12];
    const float* Wq2  = (const float*)d_in[13];
    const float* bq2  = (const float*)d_in[14];
    const float* Wk2  = (const float*)d_in[15];
    const float* bk2  = (const float*)d_in[16];
    const float* Wv2  = (const float*)d_in[17];
    const float* bv2  = (const float*)d_in[18];
    const float* We2  = (const float*)d_in[19];
    const float* Ws2  = (const float*)d_in[20];
    const float* bs2  = (const float*)d_in[21];
    float* out = (float*)d_out;

    char* ws = (char*)d_ws;
    size_t off = 0;
    auto alloc = [&](size_t bytes) -> void* {
        void* p = ws + off;
        off += (bytes + 255) & ~(size_t)255;
        return p;
    };
    int*   flag_ei = (int*)alloc(4);
    int*   flag_b  = (int*)alloc(4);
    int*   deg     = (int*)alloc((size_t)N_NODES * 4);
    int*   rowptr  = (int*)alloc((size_t)(N_NODES + 1) * 4);
    int*   rank    = (int*)alloc((size_t)N_EDGES * 4);
    int*   bsums   = (int*)alloc(64 * 4);
    u32*   edges   = (u32*)alloc((size_t)N_EDGES * 4);
    int*   gdeg    = (int*)alloc((size_t)N_GRAPHS * 4);
    int*   growptr = (int*)alloc((size_t)(N_GRAPHS + 1) * 4);
    u16*   w1T     = (u16*)alloc((size_t)1024 * 128 * 2);
    float* b1cat   = (float*)alloc(1024 * 4);
    u16*   w2T     = (u16*)alloc((size_t)896 * 256 * 2);
    float* b2cat   = (float*)alloc(896 * 4);
    u16*   B0      = (u16*)alloc((size_t)N_NODES * HC * 2);   // q1 / h1 / h2(bf16 [N,128])
    u16*   B1      = (u16*)alloc((size_t)N_NODES * HC * 2);   // skip1 / q2
    u8*    KVb     = (u8*)alloc((size_t)N_NODES * 512);       // k-fp8 | v-fp8 (both layers)
    u16*   B4      = (u16*)alloc((size_t)N_NODES * HID * 2);  // skip2

    const int E = N_EDGES;

    // 1) zero deg/gdeg + dtype detect
    init_kernel<<<61, 256, 0, stream>>>(ei, batch, deg, gdeg, flag_ei, flag_b);

    // 2) histograms (+rank capture) + weight prep
    int hp_grid = (E + N_NODES + W1_ELEMS + W2_ELEMS + 255) / 256;
    hist_prep_kernel<<<hp_grid, 256, 0, stream>>>(
        ei, batch, flag_ei, flag_b, deg, gdeg, rank,
        Wq1, Wk1, Wv1, Ws1, bq1, bk1, bv1, bs1,
        Wq2, Wk2, Wv2, Ws2, bq2, bk2, bv2, bs2,
        w1T, b1cat, w2T, b2cat);

    // 3-5) parallel scan chain
    int nb = (N_NODES + 1023) / 1024;  // 49
    scan_local_kernel<<<nb, 256, 0, stream>>>(deg, rowptr, bsums, N_NODES);
    scan_mid_kernel<<<2, 256, 0, stream>>>(bsums, nb, rowptr + N_NODES, gdeg, growptr);
    scan_add_kernel<<<(N_NODES + 255) / 256, 256, 0, stream>>>(rowptr, bsums, N_NODES);

    // 6) layer-1 GEMM (BM=128) + atomic-free edge scatter fused
    int sc_grid = (E + 255) / 256;   // 3125
    gemm1_scatter_kernel<<<GB1 + sc_grid, 256, 0, stream>>>(
        x, w1T, b1cat, B0, KVb, B1, 256, 256, N_NODES,
        ei, ea, flag_ei, rowptr, rank, edges);

    // 7) attn layer 1: h1 -> B0 (aliases q1; row-local, safe)
    attn_node<1><<<N_NODES / 4, 256, 0, stream>>>(B0, KVb, We1, B1, rowptr, edges, B0, N_NODES);

    // 8) layer-2 GEMM (BM=64): 0,1->q2(B1) 2,3->k2(fp8) 4,5->v2(fp8) 6->skip2(B4,128)
    gemm2_kernel<<<GB2, 256, 0, stream>>>(
        B0, w2T, b2cat, B1, KVb, B4, 256, 128, N_NODES);

    // 9) attn layer 2: h2 (bf16 [N,128]) -> B0
    attn_node<2><<<N_NODES / 4, 256, 0, stream>>>(B1, KVb, We2, B4, rowptr, edges, B0, N_NODES);

    // 10) pooling (bf16 h2)
    pool_kernel<<<(N_GRAPHS + 3) / 4, 256, 0, stream>>>((const u16*)B0, growptr, out);
}

// Round 15
// 434.066 us; speedup vs baseline: 1.0421x; 1.0421x over previous
//
#include <hip/hip_runtime.h>
#include <math.h>

// Problem constants (from reference)
#define N_NODES  50000
#define N_EDGES  800000
#define N_GRAPHS 2500
#define IN_DIM   128
#define HID      128
#define HEADS    2
#define HC       256   // HEADS*HID

typedef unsigned short u16;
typedef unsigned char  u8;
typedef unsigned int   u32;
typedef short  s8v  __attribute__((ext_vector_type(8)));   // 8 bf16 = 4 VGPRs (MFMA A/B frag)
typedef float  f4v  __attribute__((ext_vector_type(4)));   // MFMA C/D frag
typedef float  f2v  __attribute__((ext_vector_type(2)));

// bf16 helpers
__device__ inline float bf2f(u16 u) {
    union { unsigned int i; float f; } c; c.i = ((unsigned int)u) << 16; return c.f;
}
__device__ inline u16 f2bf(float x) {
    union { float f; unsigned int i; } c; c.f = x;
    unsigned int r = c.i + 0x7FFFu + ((c.i >> 16) & 1u);
    return (u16)(r >> 16);
}
__device__ inline float bflo(unsigned int u) {
    union { unsigned int i; float f; } c; c.i = u << 16; return c.f;
}
__device__ inline float bfhi(unsigned int u) {
    union { unsigned int i; float f; } c; c.i = u & 0xffff0000u; return c.f;
}
__device__ inline f2v mkf2(float a, float b) { f2v r; r.x = a; r.y = b; return r; }

// ---------------------------------------------------------------------------
// fp8 e4m3 encode/decode -- HW v_cvt path on gfx950, exact SW fallback
// ---------------------------------------------------------------------------
#if __has_builtin(__builtin_amdgcn_cvt_pk_fp8_f32) && __has_builtin(__builtin_amdgcn_cvt_pk_f32_fp8)
#define FP8_HW 1
#else
#define FP8_HW 0
#endif

__device__ inline u8 f2fp8(float x) {
#if FP8_HW
    return (u8)(__builtin_amdgcn_cvt_pk_fp8_f32(x, x, 0, false) & 0xff);
#else
    union { float f; unsigned int u; } c; c.f = x;
    unsigned int s = (c.u >> 24) & 0x80u;
    c.u &= 0x7fffffffu;
    if (c.f >= 448.f) return (u8)(s | 0x7e);
    if (c.f < 0.015625f) {                        // subnormal: m * 2^-9
        int m = (int)(c.f * 512.f + 0.5f);
        if (m >= 8) return (u8)(s | 0x08);
        return (u8)(s | m);
    }
    c.u += 0x000fffffu + ((c.u >> 20) & 1u);      // RNE at mantissa bit 20
    unsigned int e = ((c.u >> 23) & 0xffu) - 120u;
    unsigned int m = (c.u >> 20) & 7u;
    return (u8)(s | (e << 3) | m);
#endif
}

__device__ inline void fp8x8_to_f32(uint2 kd8, float* kf) {
#if FP8_HW
    f2v p0 = __builtin_amdgcn_cvt_pk_f32_fp8(kd8.x, false);
    f2v p1 = __builtin_amdgcn_cvt_pk_f32_fp8(kd8.x, true);
    f2v p2 = __builtin_amdgcn_cvt_pk_f32_fp8(kd8.y, false);
    f2v p3 = __builtin_amdgcn_cvt_pk_f32_fp8(kd8.y, true);
    kf[0] = p0.x; kf[1] = p0.y; kf[2] = p1.x; kf[3] = p1.y;
    kf[4] = p2.x; kf[5] = p2.y; kf[6] = p3.x; kf[7] = p3.y;
#else
#pragma unroll
    for (int i = 0; i < 8; ++i) {
        unsigned int b = ((i < 4) ? (kd8.x >> (8 * i)) : (kd8.y >> (8 * (i - 4)))) & 0xffu;
        unsigned int em = b & 0x7fu;
        union { unsigned int u; float f; } c;
        c.u = ((b & 0x80u) << 24) | ((em + 960u) << 20);   // normal decode (e+120)
        float fn = c.f;
        float fs = (float)(int)em * 0.001953125f;          // subnorm m*2^-9
        fs = (b & 0x80u) ? -fs : fs;
        kf[i] = (em >= 8u) ? fn : fs;
    }
#endif
}

// packed-pair decode: k2[0..3] = cols {0,1},{2,3},{4,5},{6,7}
__device__ inline void fp8x8_to_f2(uint2 kd8, f2v* k2) {
#if FP8_HW
    k2[0] = __builtin_amdgcn_cvt_pk_f32_fp8(kd8.x, false);
    k2[1] = __builtin_amdgcn_cvt_pk_f32_fp8(kd8.x, true);
    k2[2] = __builtin_amdgcn_cvt_pk_f32_fp8(kd8.y, false);
    k2[3] = __builtin_amdgcn_cvt_pk_f32_fp8(kd8.y, true);
#else
    float kf[8];
    fp8x8_to_f32(kd8, kf);
    k2[0] = mkf2(kf[0], kf[1]); k2[1] = mkf2(kf[2], kf[3]);
    k2[2] = mkf2(kf[4], kf[5]); k2[3] = mkf2(kf[6], kf[7]);
#endif
}

// ---------------------------------------------------------------------------
// init: blocks 0-48 zero deg, 49-58 zero gdeg, 59/60 int64-autodetect flags
// ---------------------------------------------------------------------------
__global__ __launch_bounds__(256) void init_kernel(
    const int* __restrict__ ei, const int* __restrict__ batch,
    int* __restrict__ deg, int* __restrict__ gdeg,
    int* __restrict__ flag_ei, int* __restrict__ flag_b)
{
    int b = blockIdx.x, t = threadIdx.x;
    if (b < 49) {
        int base = b * 1024 + t * 4;
        if (base + 3 < N_NODES) {
            *(int4*)&deg[base] = make_int4(0, 0, 0, 0);
        } else {
#pragma unroll
            for (int i = 0; i < 4; ++i) if (base + i < N_NODES) deg[base + i] = 0;
        }
    } else if (b < 59) {
        int i = (b - 49) * 256 + t;
        if (i < N_GRAPHS) gdeg[i] = 0;
    } else {
        const int* p = (b == 59) ? ei : batch;
        int ob = (b == 59) ? 1 : 40001;
        int* fl = (b == 59) ? flag_ei : flag_b;
        __shared__ int nz;
        if (t == 0) nz = 0;
        __syncthreads();
        int any = 0;
        for (int i = t; i < 1024; i += 256) if (p[ob + 2 * i] != 0) any = 1;
        if (any) atomicAdd(&nz, 1);
        __syncthreads();
        if (t == 0) *fl = (nz == 0) ? 1 : 0;
    }
}

// ---------------------------------------------------------------------------
// hist (edge dst + batch, rank capture) AND weight prep in one dispatch
// ---------------------------------------------------------------------------
#define W1_ELEMS (1024 * 128)
#define W2_ELEMS (896 * 256)
__global__ __launch_bounds__(256) void hist_prep_kernel(
    const int* __restrict__ ei, const int* __restrict__ batch,
    const int* __restrict__ flag_ei, const int* __restrict__ flag_b,
    int* __restrict__ deg, int* __restrict__ gdeg,
    int* __restrict__ rank,
    const float* __restrict__ Wq1, const float* __restrict__ Wk1,
    const float* __restrict__ Wv1, const float* __restrict__ Ws1,
    const float* __restrict__ bq1, const float* __restrict__ bk1,
    const float* __restrict__ bv1, const float* __restrict__ bs1,
    const float* __restrict__ Wq2, const float* __restrict__ Wk2,
    const float* __restrict__ Wv2, const float* __restrict__ Ws2,
    const float* __restrict__ bq2, const float* __restrict__ bk2,
    const float* __restrict__ bv2, const float* __restrict__ bs2,
    u16* __restrict__ w1T, float* __restrict__ b1cat,
    u16* __restrict__ w2T, float* __restrict__ b2cat)
{
    const int E = N_EDGES;
    int i = blockIdx.x * 256 + threadIdx.x;
    if (i < E) {
        int f = *flag_ei;
        int d = f ? ei[2 * ((size_t)E + i)] : ei[(size_t)E + i];
        if ((unsigned)d < (unsigned)N_NODES) rank[i] = atomicAdd(&deg[d], 1);
    } else if (i < E + N_NODES) {
        int j = i - E;
        int f = *flag_b;
        int g = f ? batch[2 * (size_t)j] : batch[j];
        if ((unsigned)g < (unsigned)N_GRAPHS) atomicAdd(&gdeg[g], 1);
    } else if (i < E + N_NODES + W1_ELEMS) {
        int t1 = i - E - N_NODES;
        int n = t1 >> 7, k = t1 & 127;
        int w = n >> 8, nc = n & 255;
        const float* W = (w == 0) ? Wq1 : (w == 1) ? Wk1 : (w == 2) ? Wv1 : Ws1;
        w1T[t1] = f2bf(W[k * 256 + nc]);
        if (k == 0) {
            const float* b = (w == 0) ? bq1 : (w == 1) ? bk1 : (w == 2) ? bv1 : bs1;
            b1cat[n] = b[nc];
        }
    } else if (i < E + N_NODES + W1_ELEMS + W2_ELEMS) {
        int t2 = i - E - N_NODES - W1_ELEMS;
        int n = t2 >> 8, k = t2 & 255;
        float val, bval;
        if (n < 768) {
            int w = n >> 8, nc = n & 255;
            const float* W = (w == 0) ? Wq2 : (w == 1) ? Wk2 : Wv2;
            val = W[k * 256 + nc];
            bval = ((w == 0) ? bq2 : (w == 1) ? bk2 : bv2)[nc];
        } else {
            val = Ws2[k * 128 + (n - 768)];
            bval = bs2[n - 768];
        }
        w2T[t2] = f2bf(val);
        if (k == 0) b2cat[n] = bval;
    }
}

// ---------------------------------------------------------------------------
// Parallel scan chain (proven)
// ---------------------------------------------------------------------------
__global__ void scan_local_kernel(const int* __restrict__ deg, int* __restrict__ rowptr,
                                  int* __restrict__ bsums, int n) {
    __shared__ int sh[256];
    int t = threadIdx.x;
    int base = blockIdx.x * 1024 + t * 4;
    int d0 = (base + 0 < n) ? deg[base + 0] : 0;
    int d1 = (base + 1 < n) ? deg[base + 1] : 0;
    int d2 = (base + 2 < n) ? deg[base + 2] : 0;
    int d3 = (base + 3 < n) ? deg[base + 3] : 0;
    sh[t] = d0 + d1 + d2 + d3;
    __syncthreads();
    for (int off = 1; off < 256; off <<= 1) {
        int val = 0;
        if (t >= off) val = sh[t - off];
        __syncthreads();
        if (t >= off) sh[t] += val;
        __syncthreads();
    }
    int excl = (t > 0) ? sh[t - 1] : 0;
    if (t == 255) bsums[blockIdx.x] = sh[255];
    if (base + 0 < n) rowptr[base + 0] = excl;
    if (base + 1 < n) rowptr[base + 1] = excl + d0;
    if (base + 2 < n) rowptr[base + 2] = excl + d0 + d1;
    if (base + 3 < n) rowptr[base + 3] = excl + d0 + d1 + d2;
}

// block 0: wave-scan of <=64 block sums (+ total); block 1: graph scan (2500)
__global__ __launch_bounds__(256) void scan_mid_kernel(
    int* __restrict__ bsums, int nb, int* __restrict__ rowptr_last,
    const int* __restrict__ gdeg, int* __restrict__ growptr)
{
    int t = threadIdx.x;
    if (blockIdx.x == 0) {
        if (t >= 64) return;
        int v = (t < nb) ? bsums[t] : 0;
        int incl = v;
        for (int off = 1; off < 64; off <<= 1) {
            int u = __shfl_up(incl, off);
            if (t >= off) incl += u;
        }
        if (t < nb) bsums[t] = incl - v;
        if (t == 63) *rowptr_last = incl;
    } else {
        __shared__ int sh[256];
        int base = t * 10;
        int loc[10];
        int s = 0;
#pragma unroll
        for (int i = 0; i < 10; ++i) {
            int v = (base + i < N_GRAPHS) ? gdeg[base + i] : 0;
            loc[i] = s; s += v;
        }
        sh[t] = s;
        __syncthreads();
        for (int off = 1; off < 256; off <<= 1) {
            int val = 0;
            if (t >= off) val = sh[t - off];
            __syncthreads();
            if (t >= off) sh[t] += val;
            __syncthreads();
        }
        int excl = (t > 0) ? sh[t - 1] : 0;
#pragma unroll
        for (int i = 0; i < 10; ++i)
            if (base + i < N_GRAPHS) growptr[base + i] = excl + loc[i];
        if (t == 255) growptr[N_GRAPHS] = sh[255];
    }
}

__global__ void scan_add_kernel(int* __restrict__ rowptr, const int* __restrict__ bsums,
                                int n) {
    int i = blockIdx.x * blockDim.x + threadIdx.x;
    if (i < n) rowptr[i] += bsums[i >> 10];
}

// ---------------------------------------------------------------------------
// BM=64 MFMA GEMM body (proven r13 floor): BK=32, XOR-swizzled LDS, swapped
// MFMA operands (packed stores), r10 register prefetch, 2 barriers.
// Five structural levers tested (stores/prefetch/barriers/atomics/tile) --
// this is the measured best; do not touch.
// KV row = k-fp8[256B] | v-fp8[256B] = 512B.
// ---------------------------------------------------------------------------
template <typename AT, int KDIM, int NT>
__device__ __forceinline__ void gemm_slab_body(
    int bx, const AT* __restrict__ A, const u16* __restrict__ BT,
    const float* __restrict__ biascat,
    u16* __restrict__ C0, u8* __restrict__ KV, u16* __restrict__ C3,
    int s0, int s3, int M)
{
    __shared__ u16 As[64 * KDIM];
    __shared__ u16 Bs[128 * 32];
    int t = threadIdx.x;
    int wid = t >> 6, lane = t & 63;
    int wm = wid >> 1, wn = wid & 1;
    int row0 = bx * 64;

    if constexpr (sizeof(AT) == 4) {
#pragma unroll
        for (int i = 0; i < KDIM / 16; ++i) {
            int c = t + i * 256;
            int row = c / (KDIM / 4);
            int kq  = (c % (KDIM / 4)) * 4;
            float4 d = make_float4(0.f, 0.f, 0.f, 0.f);
            if (row0 + row < M)
                d = *(const float4*)&A[(size_t)(row0 + row) * KDIM + kq];
            ushort4 h;
            h.x = f2bf(d.x); h.y = f2bf(d.y); h.z = f2bf(d.z); h.w = f2bf(d.w);
            *(ushort4*)&As[row * KDIM + (kq ^ ((row & 7) << 3))] = h;
        }
    } else {
#pragma unroll
        for (int i = 0; i < KDIM / 32; ++i) {
            int c = t + i * 256;
            int row = c / (KDIM / 8);
            int kq  = (c % (KDIM / 8)) * 8;
            uint4 d = make_uint4(0u, 0u, 0u, 0u);
            if (row0 + row < M)
                d = *(const uint4*)&A[(size_t)(row0 + row) * KDIM + kq];
            *(uint4*)&As[row * KDIM + (kq ^ ((row & 7) << 3))] = d;
        }
    }
    __syncthreads();

    int koff = (lane >> 4) * 8;
    int mrow = wm * 32 + (lane & 15);
    int nrow = wn * 64 + (lane & 15);
    int aswz = (lane & 7) << 3;
    int bswz = (((lane & 15) >> 1) & 3) << 3;
    int nloc = (lane >> 4) * 4;

    int c0 = t, c1 = t + 256;
    int brow0 = c0 >> 2, bkq0 = (c0 & 3) * 8;
    int brow1 = c1 >> 2, bkq1 = (c1 & 3) * 8;
    int bsa0 = brow0 * 32 + (bkq0 ^ (((brow0 >> 1) & 3) << 3));
    int bsa1 = brow1 * 32 + (bkq1 ^ (((brow1 >> 1) & 3) << 3));

    const int KS  = KDIM / 32;
    const int TOT = NT * KS;

    uint4 pb0 = *(const uint4*)&BT[(size_t)brow0 * KDIM + bkq0];
    uint4 pb1 = *(const uint4*)&BT[(size_t)brow1 * KDIM + bkq1];

    for (int nt = 0; nt < NT; ++nt) {
        f4v acc[2][4];
#pragma unroll
        for (int i = 0; i < 2; ++i)
#pragma unroll
            for (int j = 0; j < 4; ++j)
#pragma unroll
                for (int r = 0; r < 4; ++r) acc[i][j][r] = 0.f;

        for (int kk = 0; kk < KS; ++kk) {
            int k0 = kk * 32;
            int s = nt * KS + kk;
            *(uint4*)&Bs[bsa0] = pb0;
            *(uint4*)&Bs[bsa1] = pb1;
            __syncthreads();
            int s1 = s + 1;
            if (s1 < TOT) {
                int n_ = s1 / KS, k_ = (s1 % KS) * 32;
                pb0 = *(const uint4*)&BT[(size_t)(n_ * 128 + brow0) * KDIM + k_ + bkq0];
                pb1 = *(const uint4*)&BT[(size_t)(n_ * 128 + brow1) * KDIM + k_ + bkq1];
            }

            s8v af[2], bf[4];
#pragma unroll
            for (int tm = 0; tm < 2; ++tm)
                af[tm] = *(const s8v*)&As[(mrow + tm * 16) * KDIM + ((k0 + koff) ^ aswz)];
#pragma unroll
            for (int tn = 0; tn < 4; ++tn)
                bf[tn] = *(const s8v*)&Bs[(nrow + tn * 16) * 32 + (koff ^ bswz)];
#pragma unroll
            for (int tm = 0; tm < 2; ++tm)
#pragma unroll
                for (int tn = 0; tn < 4; ++tn)
                    acc[tm][tn] = __builtin_amdgcn_mfma_f32_16x16x32_bf16(
                        bf[tn], af[tm], acc[tm][tn], 0, 0, 0);
            __syncthreads();
        }

        int buf = nt >> 1;
        int colb = (nt & 1) * 128;
        float4 b4s[4];
#pragma unroll
        for (int tn = 0; tn < 4; ++tn)
            b4s[tn] = *(const float4*)&biascat[nt * 128 + wn * 64 + tn * 16 + nloc];

#pragma unroll
        for (int tm = 0; tm < 2; ++tm) {
            int row = row0 + wm * 32 + tm * 16 + (lane & 15);
            if (row >= M) continue;
#pragma unroll
            for (int tn = 0; tn < 4; ++tn) {
                int ncol = colb + wn * 64 + tn * 16 + nloc;
                float v0 = acc[tm][tn][0] + b4s[tn].x;
                float v1 = acc[tm][tn][1] + b4s[tn].y;
                float v2 = acc[tm][tn][2] + b4s[tn].z;
                float v3 = acc[tm][tn][3] + b4s[tn].w;
                if (buf == 1 || buf == 2) {
                    int off = (buf == 1) ? 0 : 256;
                    u32 pk = (u32)f2fp8(v0) | ((u32)f2fp8(v1) << 8)
                           | ((u32)f2fp8(v2) << 16) | ((u32)f2fp8(v3) << 24);
                    *(u32*)&KV[(size_t)row * 512 + off + ncol] = pk;
                } else {
                    u16* Cp = (buf == 0) ? C0 : C3;
                    int stride = (buf == 0) ? s0 : s3;
                    ushort4 h;
                    h.x = f2bf(v0); h.y = f2bf(v1); h.z = f2bf(v2); h.w = f2bf(v3);
                    *(ushort4*)&Cp[(size_t)row * stride + ncol] = h;
                }
            }
        }
    }
}

#define GB 782   // ceil(50000/64)

// Layer-1 GEMM (BM=64) with atomic-free edge scatter as trailing blocks.
// Edge record is 4B: low 16 = src (u16), high 16 = ea as bf16.
__global__ __launch_bounds__(256, 4) void gemm1_scatter_kernel(
    const float* __restrict__ A, const u16* __restrict__ BT,
    const float* __restrict__ biascat,
    u16* __restrict__ C0, u8* __restrict__ KV, u16* __restrict__ C3,
    int s0, int s3, int M,
    const int* __restrict__ ei, const float* __restrict__ ea,
    const int* __restrict__ flag, const int* __restrict__ rowptr,
    const int* __restrict__ rank, u32* __restrict__ edges)
{
    if (blockIdx.x < GB) {
        gemm_slab_body<float, 128, 8>(blockIdx.x, A, BT, biascat,
                                      C0, KV, C3, s0, s3, M);
    } else {
        const int E = N_EDGES;
        int i = (blockIdx.x - GB) * 256 + threadIdx.x;
        if (i >= E) return;
        int f = *flag;
        int s = f ? ei[2 * (size_t)i] : ei[i];
        int d = f ? ei[2 * ((size_t)E + i)] : ei[(size_t)E + i];
        if ((unsigned)d >= (unsigned)N_NODES) return;
        if ((unsigned)s >= (unsigned)N_NODES) s = 0;
        int p = rowptr[d] + rank[i];
        u32 rec = (u32)(s & 0xffff) | ((u32)f2bf(ea[i]) << 16);
        edges[p] = rec;
    }
}

__global__ __launch_bounds__(256, 4) void gemm2_kernel(
    const u16* __restrict__ A, const u16* __restrict__ BT,
    const float* __restrict__ biascat,
    u16* __restrict__ C0, u8* __restrict__ KV, u16* __restrict__ C3,
    int s0, int s3, int M)
{
    gemm_slab_body<u16, 256, 7>(blockIdx.x, A, BT, biascat,
                                C0, KV, C3, s0, s3, M);
}

// ---------------------------------------------------------------------------
// Attention: wave per node, 8 cols/lane, 8 edges/step (4 per 32-lane half).
// No online max (reference-invariant softmax, alpha O(1), exp2 clamp 80).
// KV row (512B): k-fp8[256B] | v-fp8[256B].  Edge rec 4B: u16 src | bf16 ae.
// LAYER==2 writes h2 as bf16 (feeds only the mean-pool; halves the traffic).
// ---------------------------------------------------------------------------
template <int LAYER>
__global__ __launch_bounds__(256) void attn_node(
    const u16* __restrict__ q, const u8* __restrict__ kv,
    const float* __restrict__ We, const u16* __restrict__ skip,
    const int* __restrict__ rowptr, const u32* __restrict__ edges,
    void* __restrict__ hout, int N)
{
    int wave = (blockIdx.x * blockDim.x + threadIdx.x) >> 6;
    int lane = threadIdx.x & 63;
    if (wave >= N) return;
    int n = wave;
    int half = lane >> 5;
    int cl   = lane & 31;
    // scale * log2(e) = (1/sqrt(128)) * 1.4426950408889634
    const float scale2 = 0.12751743558136835f;

    uint4 qd = *(const uint4*)&q[(size_t)n * HC + cl * 8];
    f2v q2[4];
    q2[0] = mkf2(bflo(qd.x), bfhi(qd.x));
    q2[1] = mkf2(bflo(qd.y), bfhi(qd.y));
    q2[2] = mkf2(bflo(qd.z), bfhi(qd.z));
    q2[3] = mkf2(bflo(qd.w), bfhi(qd.w));
    float4 wlo = *(const float4*)&We[cl * 8];
    float4 whi = *(const float4*)&We[cl * 8 + 4];
    f2v w2[4];
    w2[0] = mkf2(wlo.x, wlo.y); w2[1] = mkf2(wlo.z, wlo.w);
    w2[2] = mkf2(whi.x, whi.y); w2[3] = mkf2(whi.z, whi.w);

    f2v qw2 = q2[0] * w2[0];
    qw2 += q2[1] * w2[1];
    qw2 += q2[2] * w2[2];
    qw2 += q2[3] * w2[3];
    float qw = qw2.x + qw2.y;
    qw += __shfl_xor(qw, 1);
    qw += __shfl_xor(qw, 2);
    qw += __shfl_xor(qw, 4);
    qw += __shfl_xor(qw, 8);

    int e0 = rowptr[n], e1 = rowptr[n + 1];
    float ll0 = 0.f, ll1 = 0.f;
    float pa0 = 0.f, pa1 = 0.f;
    f2v a0[4], a1[4];
#pragma unroll
    for (int i = 0; i < 4; ++i) { a0[i] = mkf2(0.f, 0.f); a1[i] = mkf2(0.f, 0.f); }

    int steps = (e1 - e0 + 7) >> 3;
    for (int st = 0; st < steps; ++st) {
        int eb = e0 + 8 * st + half;
        u32 rec[4]; bool act[4];
#pragma unroll
        for (int j = 0; j < 4; ++j) {
            int ex = eb + 2 * j;
            act[j] = ex < e1;
            rec[j] = edges[act[j] ? ex : e0];
        }
        uint2 kd[4], vd[4]; float ae[4];
#pragma unroll
        for (int j = 0; j < 4; ++j) {
            const u8* base = kv + (size_t)(rec[j] & 0xffffu) * 512;
            kd[j] = *(const uint2*)(base + cl * 8);
            vd[j] = *(const uint2*)(base + 256 + cl * 8);
            ae[j] = bfhi(rec[j]);
        }
#pragma unroll
        for (int j = 0; j < 4; ++j) {
            f2v k2[4], v2[4];
            fp8x8_to_f2(kd[j], k2);
            fp8x8_to_f2(vd[j], v2);
            f2v d2 = q2[0] * k2[0];
            d2 += q2[1] * k2[1];
            d2 += q2[2] * k2[2];
            d2 += q2[3] * k2[3];
            float d = d2.x + d2.y;
            d += __shfl_xor(d, 1);
            d += __shfl_xor(d, 2);
            d += __shfl_xor(d, 4);
            d += __shfl_xor(d, 8);
            float alpha = act[j] ? fmaf(ae[j], qw, d) * scale2 : -16384.f;
            float p = exp2f(fminf(alpha, 80.f));
            f2v p2 = mkf2(p, p);
            if (j & 1) {
                ll1 += p;
                pa1 = fmaf(p, ae[j], pa1);
                a1[0] += p2 * v2[0];
                a1[1] += p2 * v2[1];
                a1[2] += p2 * v2[2];
                a1[3] += p2 * v2[3];
            } else {
                ll0 += p;
                pa0 = fmaf(p, ae[j], pa0);
                a0[0] += p2 * v2[0];
                a0[1] += p2 * v2[1];
                a0[2] += p2 * v2[2];
                a0[3] += p2 * v2[3];
            }
        }
    }

    float l = ll0 + ll1;
    float pa = pa0 + pa1;
    float acc[8];
#pragma unroll
    for (int i = 0; i < 4; ++i) {
        f2v v = a0[i] + a1[i];
        acc[2 * i] = v.x; acc[2 * i + 1] = v.y;
    }

    l += __shfl_xor(l, 32);
    pa += __shfl_xor(pa, 32);
#pragma unroll
    for (int i = 0; i < 8; ++i) acc[i] += __shfl_xor(acc[i], 32);

    float wf[8];
    wf[0] = w2[0].x; wf[1] = w2[0].y; wf[2] = w2[1].x; wf[3] = w2[1].y;
    wf[4] = w2[2].x; wf[5] = w2[2].y; wf[6] = w2[3].x; wf[7] = w2[3].y;

    float inv = (l > 0.f) ? 1.f / l : 0.f;
    float o[8];
#pragma unroll
    for (int i = 0; i < 8; ++i) o[i] = fmaf(pa, wf[i], acc[i]) * inv;

    if constexpr (LAYER == 1) {
        if (half == 0) {
            uint4 sd = *(const uint4*)&skip[(size_t)n * HC + cl * 8];
            float sf[8];
            sf[0] = bflo(sd.x); sf[1] = bfhi(sd.x);
            sf[2] = bflo(sd.y); sf[3] = bfhi(sd.y);
            sf[4] = bflo(sd.z); sf[5] = bfhi(sd.z);
            sf[6] = bflo(sd.w); sf[7] = bfhi(sd.w);
            ushort4 o4a, o4b;
            o4a.x = f2bf(fmaxf(0.f, o[0] + sf[0]));
            o4a.y = f2bf(fmaxf(0.f, o[1] + sf[1]));
            o4a.z = f2bf(fmaxf(0.f, o[2] + sf[2]));
            o4a.w = f2bf(fmaxf(0.f, o[3] + sf[3]));
            o4b.x = f2bf(fmaxf(0.f, o[4] + sf[4]));
            o4b.y = f2bf(fmaxf(0.f, o[5] + sf[5]));
            o4b.z = f2bf(fmaxf(0.f, o[6] + sf[6]));
            o4b.w = f2bf(fmaxf(0.f, o[7] + sf[7]));
            u16* hp = (u16*)hout + (size_t)n * HC + cl * 8;
            *(ushort4*)hp = o4a;
            *(ushort4*)(hp + 4) = o4b;
        }
    } else {
#pragma unroll
        for (int i = 0; i < 8; ++i) {
            float t2 = __shfl_xor(o[i], 16);
            o[i] = 0.5f * (o[i] + t2);
        }
        if (lane < 16) {
            uint4 sd = *(const uint4*)&skip[(size_t)n * HID + lane * 8];
            float sf[8];
            sf[0] = bflo(sd.x); sf[1] = bfhi(sd.x);
            sf[2] = bflo(sd.y); sf[3] = bfhi(sd.y);
            sf[4] = bflo(sd.z); sf[5] = bfhi(sd.z);
            sf[6] = bflo(sd.w); sf[7] = bfhi(sd.w);
            ushort4 h2a, h2b;
            h2a.x = f2bf(o[0] + sf[0]); h2a.y = f2bf(o[1] + sf[1]);
            h2a.z = f2bf(o[2] + sf[2]); h2a.w = f2bf(o[3] + sf[3]);
            h2b.x = f2bf(o[4] + sf[4]); h2b.y = f2bf(o[5] + sf[5]);
            h2b.z = f2bf(o[6] + sf[6]); h2b.w = f2bf(o[7] + sf[7]);
            u16* hp = (u16*)hout + (size_t)n * HID + lane * 8;
            *(ushort4*)hp = h2a;
            *(ushort4*)(hp + 4) = h2b;
        }
    }
}

// ---------------------------------------------------------------------------
// Atomic-free pooling over bf16 h2: one wave per graph (batch is sorted)
// ---------------------------------------------------------------------------
__global__ __launch_bounds__(256) void pool_kernel(
    const u16* __restrict__ h2, const int* __restrict__ growptr,
    float* __restrict__ out) {
    int wave = (blockIdx.x * blockDim.x + threadIdx.x) >> 6;
    int lane = threadIdx.x & 63;
    if (wave >= N_GRAPHS) return;
    int r0 = growptr[wave], r1 = growptr[wave + 1];
    float sx = 0.f, sy = 0.f;
    for (int r = r0; r < r1; ++r) {
        u32 v = *(const u32*)&h2[(size_t)r * HID + lane * 2];
        sx += bflo(v); sy += bfhi(v);
    }
    float inv = 1.f / fmaxf((float)(r1 - r0), 1.f);
    float2 o; o.x = sx * inv; o.y = sy * inv;
    *(float2*)&out[(size_t)wave * HID + lane * 2] = o;
}

// ---------------------------------------------------------------------------
// Launch: 10 dispatches. ws ~100 MB. KV row = k-fp8[256B] | v-fp8[256B].
// Edge records 4B. Scatter rank-based. gemm1 BM=64 (r13 best). h2 bf16.
// ---------------------------------------------------------------------------
extern "C" void kernel_launch(void* const* d_in, const int* in_sizes, int n_in,
                              void* d_out, int out_size, void* d_ws, size_t ws_size,
                              hipStream_t stream) {
    const float* x    = (const float*)d_in[0];
    const int*   ei   = (const int*)d_in[1];
    const int*   batch= (const int*)d_in[2];
    const float* ea   = (const float*)d_in[3];
    const float* Wq1  = (const float*)d_in[4];
    const float* bq1  = (const float*)d_in[5];
    const float* Wk1  = (const float*)d_in[6];
    const float* bk1  = (const float*)d_in[7];
    const float* Wv1  = (const float*)d_in[8];
    const float* bv1  = (const float*)d_in[9];
    const float* We1  = (const float*)d_in[10];
    const float* Ws1  = (const float*)d_in[11];
    const float* bs1  = (const float*)d_in[12];
    const float* Wq2  = (const float*)d_in[13];
    const float* bq2  = (const float*)d_in[14];
    const float* Wk2  = (const float*)d_in[15];
    const float* bk2  = (const float*)d_in[16];
    const float* Wv2  = (const float*)d_in[17];
    const float* bv2  = (const float*)d_in[18];
    const float* We2  = (const float*)d_in[19];
    const float* Ws2  = (const float*)d_in[20];
    const float* bs2  = (const float*)d_in[21];
    float* out = (float*)d_out;

    char* ws = (char*)d_ws;
    size_t off = 0;
    auto alloc = [&](size_t bytes) -> void* {
        void* p = ws + off;
        off += (bytes + 255) & ~(size_t)255;
        return p;
    };
    int*   flag_ei = (int*)alloc(4);
    int*   flag_b  = (int*)alloc(4);
    int*   deg     = (int*)alloc((size_t)N_NODES * 4);
    int*   rowptr  = (int*)alloc((size_t)(N_NODES + 1) * 4);
    int*   rank    = (int*)alloc((size_t)N_EDGES * 4);
    int*   bsums   = (int*)alloc(64 * 4);
    u32*   edges   = (u32*)alloc((size_t)N_EDGES * 4);
    int*   gdeg    = (int*)alloc((size_t)N_GRAPHS * 4);
    int*   growptr = (int*)alloc((size_t)(N_GRAPHS + 1) * 4);
    u16*   w1T     = (u16*)alloc((size_t)1024 * 128 * 2);
    float* b1cat   = (float*)alloc(1024 * 4);
    u16*   w2T     = (u16*)alloc((size_t)896 * 256 * 2);
    float* b2cat   = (float*)alloc(896 * 4);
    u16*   B0      = (u16*)alloc((size_t)N_NODES * HC * 2);   // q1 / h1 / h2(bf16 [N,128])
    u16*   B1      = (u16*)alloc((size_t)N_NODES * HC * 2);   // skip1 / q2
    u8*    KVb     = (u8*)alloc((size_t)N_NODES * 512);       // k-fp8 | v-fp8 (both layers)
    u16*   B4      = (u16*)alloc((size_t)N_NODES * HID * 2);  // skip2

    const int E = N_EDGES;

    // 1) zero deg/gdeg + dtype detect
    init_kernel<<<61, 256, 0, stream>>>(ei, batch, deg, gdeg, flag_ei, flag_b);

    // 2) histograms (+rank capture) + weight prep
    int hp_grid = (E + N_NODES + W1_ELEMS + W2_ELEMS + 255) / 256;
    hist_prep_kernel<<<hp_grid, 256, 0, stream>>>(
        ei, batch, flag_ei, flag_b, deg, gdeg, rank,
        Wq1, Wk1, Wv1, Ws1, bq1, bk1, bv1, bs1,
        Wq2, Wk2, Wv2, Ws2, bq2, bk2, bv2, bs2,
        w1T, b1cat, w2T, b2cat);

    // 3-5) parallel scan chain
    int nb = (N_NODES + 1023) / 1024;  // 49
    scan_local_kernel<<<nb, 256, 0, stream>>>(deg, rowptr, bsums, N_NODES);
    scan_mid_kernel<<<2, 256, 0, stream>>>(bsums, nb, rowptr + N_NODES, gdeg, growptr);
    scan_add_kernel<<<(N_NODES + 255) / 256, 256, 0, stream>>>(rowptr, bsums, N_NODES);

    // 6) layer-1 GEMM (BM=64) + atomic-free edge scatter fused
    int sc_grid = (E + 255) / 256;   // 3125
    gemm1_scatter_kernel<<<GB + sc_grid, 256, 0, stream>>>(
        x, w1T, b1cat, B0, KVb, B1, 256, 256, N_NODES,
        ei, ea, flag_ei, rowptr, rank, edges);

    // 7) attn layer 1: h1 -> B0 (aliases q1; row-local, safe)
    attn_node<1><<<N_NODES / 4, 256, 0, stream>>>(B0, KVb, We1, B1, rowptr, edges, B0, N_NODES);

    // 8) layer-2 GEMM (BM=64): 0,1->q2(B1) 2,3->k2(fp8) 4,5->v2(fp8) 6->skip2(B4,128)
    gemm2_kernel<<<GB, 256, 0, stream>>>(
        B0, w2T, b2cat, B1, KVb, B4, 256, 128, N_NODES);

    // 9) attn layer 2: h2 (bf16 [N,128]) -> B0
    attn_node<2><<<N_NODES / 4, 256, 0, stream>>>(B1, KVb, We2, B4, rowptr, edges, B0, N_NODES);

    // 10) pooling (bf16 h2)
    pool_kernel<<<(N_GRAPHS + 3) / 4, 256, 0, stream>>>((const u16*)B0, growptr, out);
}